// Round 14
// baseline (622.127 us; speedup 1.0000x reference)
//
#include <hip/hip_runtime.h>
#include <hip/hip_bf16.h>

#define GENES 20000
#define DD    128
#define PP    32
#define HH    128
#define NB    4096
#define GOUT  20000
#define GPAD  20096   // GOUT padded to multiple of 128
#define CPB   16      // combos per encoder block
#define RG    3       // out_gemm measurement reps

typedef __attribute__((ext_vector_type(8))) short bf16x8;
typedef __attribute__((ext_vector_type(4))) float f32x4;

__device__ __forceinline__ unsigned short f2bf(float f) {
    unsigned int u = __float_as_uint(f);
    unsigned int lsb = (u >> 16) & 1u;
    u += 0x7fffu + lsb;                      // RTNE
    return (unsigned short)(u >> 16);
}
__device__ __forceinline__ float bf2f(unsigned short s) {
    return __uint_as_float(((unsigned int)s) << 16);
}

// XOR-swizzled ushort offset inside a [rows][128] bf16 tile (16B-chunk swizzle).
__device__ __forceinline__ int swz(int r, int c) {
    return r * 128 + (((c >> 3) ^ (r & 15)) << 3) + (c & 7);
}

// ---------------- K0a: W1,W2 -> swizzled bf16 transposed tiles ----------------
__global__ void prep_weights(const float* __restrict__ W1, const float* __restrict__ W2,
                             unsigned short* __restrict__ w1t, unsigned short* __restrict__ w2t) {
    int idx = blockIdx.x * 512 + threadIdx.x;
#pragma unroll
    for (int k = 0; k < 2; ++k, idx += 256) {
        int d = idx >> 7, h = idx & 127;
        int off = swz(h, d);       // W1T[h][d] = W1[d][h]
        w1t[off] = f2bf(W1[idx]);
        w2t[off] = f2bf(W2[idx]);
    }
}

// ---------------- K0b: Wout [128][20000] f32 -> WoutT [20096][128] bf16 -------
__global__ void prep_wout(const float* __restrict__ Wout, unsigned short* __restrict__ woutT) {
    int g = blockIdx.x * 256 + threadIdx.x;
    if (g >= GPAD) return;
    if (g < GOUT) {
        for (int d0 = 0; d0 < 128; d0 += 8) {
            unsigned short buf[8];
#pragma unroll
            for (int j = 0; j < 8; ++j) buf[j] = f2bf(Wout[(size_t)(d0 + j) * GOUT + g]);
            *reinterpret_cast<uint4*>(&woutT[(size_t)g * 128 + d0]) =
                *reinterpret_cast<const uint4*>(buf);
        }
    } else {
        uint4 z = {0u, 0u, 0u, 0u};
        for (int d0 = 0; d0 < 128; d0 += 8)
            *reinterpret_cast<uint4*>(&woutT[(size_t)g * 128 + d0]) = z;
    }
}

// ---------------- K1: persistent encoder, pipelined gather (R2 exact) ---------
__global__ __launch_bounds__(512) void encoder_kernel(
    const float* __restrict__ gene, const float* __restrict__ b1g,
    const float* __restrict__ b2g, const float* __restrict__ pwg,
    const int* __restrict__ locs_gene, const int* __restrict__ locs_combos,
    const unsigned short* __restrict__ w1t, const unsigned short* __restrict__ w2t,
    unsigned short* __restrict__ poolbf)
{
    __shared__ __align__(16) unsigned short w1L[128 * 128];     // 32 KB swizzled
    __shared__ __align__(16) unsigned short w2L[128 * 128];     // 32 KB swizzled
    __shared__ __align__(16) unsigned short aBuf[2][64 * 128];  // 2 x 16 KB swizzled
    __shared__ float wrow[64];
    __shared__ float pp[8][128];

    const int t = threadIdx.x;
    const int lane = t & 63, wv = t >> 6;
    const int nrow = lane & 15, kg = lane >> 4;
    const int mt = wv >> 1, nh = wv & 1;          // wave -> (M-tile, N-half)
    const int rA = mt * 16 + nrow;

    // ---- stage weights once per block
    {
        const uint4* s1 = reinterpret_cast<const uint4*>(w1t);
        const uint4* s2 = reinterpret_cast<const uint4*>(w2t);
        uint4* d1 = reinterpret_cast<uint4*>(w1L);
        uint4* d2 = reinterpret_cast<uint4*>(w2L);
        for (int i = t; i < 2048; i += 512) { d1[i] = s1[i]; d2[i] = s2[i]; }
    }
    // ---- per-thread invariants
    float b1r[4], b2r[4];
#pragma unroll
    for (int nt = 0; nt < 4; ++nt) {
        int c = nh * 64 + nt * 16 + nrow;
        b1r[nt] = b1g[c]; b2r[nt] = b2g[c];
    }
    const float pwl = pwg[lane & 31];

    // staging decomposition: thread -> (gene slot, d-quad, p-quad)
    const int sl = t >> 8;                 // 0..1 (which gene of the combo)
    const int w8 = t & 255;
    const int d0 = (w8 >> 3) * 4;          // 0,4,...,124
    const int pq = w8 & 7;                 // p-quad 0..7

    const int c0 = blockIdx.x * CPB;

    float4 pf[4];
    // ---- prologue: load + stage combo c0 into aBuf[0]
    {
        int g0 = locs_gene[2 * c0], g1 = locs_gene[2 * c0 + 1];
        const float* src = gene + (size_t)(sl ? g1 : g0) * 4096;
#pragma unroll
        for (int i = 0; i < 4; ++i)
            pf[i] = *reinterpret_cast<const float4*>(&src[(d0 + i) * 32 + pq * 4]);
#pragma unroll
        for (int q = 0; q < 4; ++q) {
            int r = sl * 32 + pq * 4 + q;
            unsigned int lo = (unsigned int)f2bf((&pf[0].x)[q]) |
                              ((unsigned int)f2bf((&pf[1].x)[q]) << 16);
            unsigned int hi = (unsigned int)f2bf((&pf[2].x)[q]) |
                              ((unsigned int)f2bf((&pf[3].x)[q]) << 16);
            uint2 v2 = {lo, hi};
            *reinterpret_cast<uint2*>(
                &aBuf[0][r * 128 + (((d0 >> 3) ^ (r & 15)) << 3) + (d0 & 7)]) = v2;
        }
    }
    __syncthreads();

    int cur = 0;
    for (int j = 0; j < CPB; ++j) {
        const int c = c0 + j;
        // ---- issue prefetch loads for combo c+1 (latency hides under MFMA)
        if (j + 1 < CPB) {
            int g0 = locs_gene[2 * (c + 1)], g1 = locs_gene[2 * (c + 1) + 1];
            const float* src = gene + (size_t)(sl ? g1 : g0) * 4096;
#pragma unroll
            for (int i = 0; i < 4; ++i)
                pf[i] = *reinterpret_cast<const float4*>(&src[(d0 + i) * 32 + pq * 4]);
        }
        const unsigned short* A = aBuf[cur];
        unsigned short* Aw = aBuf[cur];

        // ---- wave 0: per-row colsum -> mask -> softmax -> wrow[64]
        if (wv == 0) {
            float cs = 0.f;
#pragma unroll
            for (int cch = 0; cch < 16; ++cch) {
                int phys = cch ^ (lane & 15);
                bf16x8 v = *reinterpret_cast<const bf16x8*>(&A[lane * 128 + phys * 8]);
#pragma unroll
                for (int q = 0; q < 8; ++q) cs += bf2f((unsigned short)v[q]);
            }
            float other = __shfl_down(cs, 32);
            bool m = (cs != 0.f) || (other != 0.f);
            float logit = m ? pwl : -1e9f;
            float mx = logit;
#pragma unroll
            for (int o = 16; o >= 1; o >>= 1) mx = fmaxf(mx, __shfl_xor(mx, o, 32));
            float e = __expf(logit - mx);
            float se = e;
#pragma unroll
            for (int o = 16; o >= 1; o >>= 1) se += __shfl_xor(se, o, 32);
            float w = e / se;
            if (lane < 32) { wrow[lane] = w; wrow[lane + 32] = w; }
        }

        // ---- layer 1: H1 = leaky(A @ W1 + b1)
        bf16x8 afr[4];
#pragma unroll
        for (int ks = 0; ks < 4; ++ks) {
            int phys = (ks * 4 + kg) ^ (rA & 15);
            afr[ks] = *reinterpret_cast<const bf16x8*>(&A[rA * 128 + phys * 8]);
        }
        f32x4 acc1[4];
#pragma unroll
        for (int nt = 0; nt < 4; ++nt) {
            f32x4 acc = {0.f, 0.f, 0.f, 0.f};
            int n = nh * 64 + nt * 16 + nrow;
#pragma unroll
            for (int ks = 0; ks < 4; ++ks) {
                int phys = (ks * 4 + kg) ^ (n & 15);
                bf16x8 bfr = *reinterpret_cast<const bf16x8*>(&w1L[n * 128 + phys * 8]);
                acc = __builtin_amdgcn_mfma_f32_16x16x32_bf16(afr[ks], bfr, acc, 0, 0, 0);
            }
            acc1[nt] = acc;
        }
        __syncthreads();   // (1) all aBuf[cur] reads + wrow write done

        // ---- write H1 back into aBuf[cur] (swizzled)
#pragma unroll
        for (int nt = 0; nt < 4; ++nt) {
            int cc = nh * 64 + nt * 16 + nrow;
#pragma unroll
            for (int i = 0; i < 4; ++i) {
                int r = mt * 16 + kg * 4 + i;
                float x = acc1[nt][i] + b1r[nt];
                x = (x >= 0.f) ? x : 0.01f * x;
                Aw[swz(r, cc)] = f2bf(x);
            }
        }
        __syncthreads();   // (2) H1 visible

        // ---- layer 2 + leaky + weighted pooling
        bf16x8 afr2[4];
#pragma unroll
        for (int ks = 0; ks < 4; ++ks) {
            int phys = (ks * 4 + kg) ^ (rA & 15);
            afr2[ks] = *reinterpret_cast<const bf16x8*>(&A[rA * 128 + phys * 8]);
        }
        float wr[4];
#pragma unroll
        for (int i = 0; i < 4; ++i) wr[i] = wrow[mt * 16 + kg * 4 + i];
        float part[4];
#pragma unroll
        for (int nt = 0; nt < 4; ++nt) {
            f32x4 acc = {0.f, 0.f, 0.f, 0.f};
            int n = nh * 64 + nt * 16 + nrow;
#pragma unroll
            for (int ks = 0; ks < 4; ++ks) {
                int phys = (ks * 4 + kg) ^ (n & 15);
                bf16x8 bfr = *reinterpret_cast<const bf16x8*>(&w2L[n * 128 + phys * 8]);
                acc = __builtin_amdgcn_mfma_f32_16x16x32_bf16(afr2[ks], bfr, acc, 0, 0, 0);
            }
            float s = 0.f;
#pragma unroll
            for (int i = 0; i < 4; ++i) {
                float x = acc[i] + b2r[nt];
                x = (x >= 0.f) ? x : 0.01f * x;
                s += x * wr[i];
            }
            part[nt] = s;
        }
#pragma unroll
        for (int nt = 0; nt < 4; ++nt) {
            float v = part[nt];
            v += __shfl_xor(v, 16);
            v += __shfl_xor(v, 32);
            part[nt] = v;
        }
        if (lane < 16) {
#pragma unroll
            for (int nt = 0; nt < 4; ++nt) pp[wv][nh * 64 + nt * 16 + lane] = part[nt];
        }
        __syncthreads();   // (3) pp complete

        if (t < 128) {
            int base = t >> 6;
            float s = pp[base][t] + pp[base + 2][t] + pp[base + 4][t] + pp[base + 6][t];
            int seg = locs_combos[2 * c];
            poolbf[(size_t)seg * 128 + t] = f2bf(s);
        }
        // ---- stage combo c+1 into aBuf[cur^1]
        if (j + 1 < CPB) {
            unsigned short* B = aBuf[cur ^ 1];
#pragma unroll
            for (int q = 0; q < 4; ++q) {
                int r = sl * 32 + pq * 4 + q;
                unsigned int lo = (unsigned int)f2bf((&pf[0].x)[q]) |
                                  ((unsigned int)f2bf((&pf[1].x)[q]) << 16);
                unsigned int hi = (unsigned int)f2bf((&pf[2].x)[q]) |
                                  ((unsigned int)f2bf((&pf[3].x)[q]) << 16);
                uint2 v2 = {lo, hi};
                *reinterpret_cast<uint2*>(
                    &B[r * 128 + (((d0 >> 3) ^ (r & 15)) << 3) + (d0 & 7)]) = v2;
            }
            cur ^= 1;
        }
        __syncthreads();   // (4) aBuf[next] ready; pp reads done
    }
}

// ---------------- K2a: R13 out_gemm (LDS epilogue), amplified x RG ------------
__global__ __launch_bounds__(256, 3) void out_gemm_a(
    const unsigned short* __restrict__ poolbf, const unsigned short* __restrict__ woutT,
    const float* __restrict__ boutg, float* __restrict__ out)
{
    __shared__ float tile[128][68];            // 34.8 KB
    const int t = threadIdx.x;
    const int lane = t & 63, wv = t >> 6;
    const int nrow = lane & 15, kg = lane >> 4;
    const int nb0 = blockIdx.x * 128;
    const int mb0 = wv * 32;

#pragma unroll 1
    for (int rep = 0; rep < RG; ++rep) {
#pragma unroll 1
    for (int p = 0; p < 2; ++p) {
        bf16x8 afr[4][4];
#pragma unroll
        for (int q = 0; q < 4; ++q) {
            int g = nb0 + (p * 4 + q) * 16 + nrow;
#pragma unroll
            for (int ks = 0; ks < 4; ++ks)
                afr[q][ks] = *reinterpret_cast<const bf16x8*>(
                    &woutT[(size_t)g * 128 + ks * 32 + kg * 8]);
        }
#pragma unroll 1
        for (int sub = 0; sub < 4; ++sub) {
            const int brow0 = (blockIdx.y * 4 + sub) * 128;
            bf16x8 bfr[2][4];
#pragma unroll
            for (int bt = 0; bt < 2; ++bt) {
                int row = brow0 + mb0 + bt * 16 + nrow;
#pragma unroll
                for (int ks = 0; ks < 4; ++ks)
                    bfr[bt][ks] = *reinterpret_cast<const bf16x8*>(
                        &poolbf[(size_t)row * 128 + ks * 32 + kg * 8]);
            }
            f32x4 acc[4][2];
#pragma unroll
            for (int q = 0; q < 4; ++q) {
                f32x4 a0 = {0.f, 0.f, 0.f, 0.f}, a1 = {0.f, 0.f, 0.f, 0.f};
#pragma unroll
                for (int ks = 0; ks < 4; ++ks) {
                    a0 = __builtin_amdgcn_mfma_f32_16x16x32_bf16(afr[q][ks], bfr[0][ks], a0, 0, 0, 0);
                    a1 = __builtin_amdgcn_mfma_f32_16x16x32_bf16(afr[q][ks], bfr[1][ks], a1, 0, 0, 0);
                }
                acc[q][0] = a0; acc[q][1] = a1;
            }
            __syncthreads();
#pragma unroll
            for (int q = 0; q < 4; ++q) {
                int gcol = nb0 + (p * 4 + q) * 16 + kg * 4;
                float4 b4 = {0.f, 0.f, 0.f, 0.f};
                if (gcol < GOUT) b4 = *reinterpret_cast<const float4*>(&boutg[gcol]);
                int gl = q * 16 + kg * 4;
#pragma unroll
                for (int bt = 0; bt < 2; ++bt) {
                    int row = mb0 + bt * 16 + nrow;
                    float4 o;
                    o.x = acc[q][bt][0] + b4.x; o.y = acc[q][bt][1] + b4.y;
                    o.z = acc[q][bt][2] + b4.z; o.w = acc[q][bt][3] + b4.w;
                    *reinterpret_cast<float4*>(&tile[row][gl]) = o;
                }
            }
            __syncthreads();
            int cl = (t & 15) * 4;
            int gcol = nb0 + p * 64 + cl;
            if (gcol < GOUT) {
#pragma unroll
                for (int rnd = 0; rnd < 8; ++rnd) {
                    int rl = rnd * 16 + (t >> 4);
                    f32x4 v = *reinterpret_cast<const f32x4*>(&tile[rl][cl]);
                    __builtin_nontemporal_store(
                        v, reinterpret_cast<f32x4*>(&out[(size_t)(brow0 + rl) * GOUT + gcol]));
                }
            }
        }
    }
    }
}

// ---------------- K2b: direct-store variant (no LDS, no barriers), x RG -------
// Same math/layout as K2a; stores go straight from the transposed-layout acc
// (4 lanes x 16 B = 64 B contiguous per row, 16 rows per instr). Tests whether
// K2a's per-sub barrier+LDS serialization is the remaining cost.
__global__ __launch_bounds__(256, 3) void out_gemm_b(
    const unsigned short* __restrict__ poolbf, const unsigned short* __restrict__ woutT,
    const float* __restrict__ boutg, float* __restrict__ out)
{
    const int t = threadIdx.x;
    const int lane = t & 63, wv = t >> 6;
    const int nrow = lane & 15, kg = lane >> 4;
    const int nb0 = blockIdx.x * 128;
    const int mb0 = wv * 32;

#pragma unroll 1
    for (int rep = 0; rep < RG; ++rep) {
#pragma unroll 1
    for (int p = 0; p < 2; ++p) {
        bf16x8 afr[4][4];
        float4 bias[4];
#pragma unroll
        for (int q = 0; q < 4; ++q) {
            int g = nb0 + (p * 4 + q) * 16 + nrow;
#pragma unroll
            for (int ks = 0; ks < 4; ++ks)
                afr[q][ks] = *reinterpret_cast<const bf16x8*>(
                    &woutT[(size_t)g * 128 + ks * 32 + kg * 8]);
            int gcol = nb0 + (p * 4 + q) * 16 + kg * 4;
            float4 b4 = {0.f, 0.f, 0.f, 0.f};
            if (gcol < GOUT) b4 = *reinterpret_cast<const float4*>(&boutg[gcol]);
            bias[q] = b4;
        }
#pragma unroll 1
        for (int sub = 0; sub < 4; ++sub) {
            const int brow0 = (blockIdx.y * 4 + sub) * 128;
            bf16x8 bfr[2][4];
#pragma unroll
            for (int bt = 0; bt < 2; ++bt) {
                int row = brow0 + mb0 + bt * 16 + nrow;
#pragma unroll
                for (int ks = 0; ks < 4; ++ks)
                    bfr[bt][ks] = *reinterpret_cast<const bf16x8*>(
                        &poolbf[(size_t)row * 128 + ks * 32 + kg * 8]);
            }
#pragma unroll
            for (int q = 0; q < 4; ++q) {
                f32x4 a0 = {0.f, 0.f, 0.f, 0.f}, a1 = {0.f, 0.f, 0.f, 0.f};
#pragma unroll
                for (int ks = 0; ks < 4; ++ks) {
                    a0 = __builtin_amdgcn_mfma_f32_16x16x32_bf16(afr[q][ks], bfr[0][ks], a0, 0, 0, 0);
                    a1 = __builtin_amdgcn_mfma_f32_16x16x32_bf16(afr[q][ks], bfr[1][ks], a1, 0, 0, 0);
                }
                int gs = nb0 + (p * 4 + q) * 16 + kg * 4;
                if (gs < GOUT) {
                    f32x4 o0, o1;
                    o0[0] = a0[0] + bias[q].x; o0[1] = a0[1] + bias[q].y;
                    o0[2] = a0[2] + bias[q].z; o0[3] = a0[3] + bias[q].w;
                    o1[0] = a1[0] + bias[q].x; o1[1] = a1[1] + bias[q].y;
                    o1[2] = a1[2] + bias[q].z; o1[3] = a1[3] + bias[q].w;
                    int row0 = brow0 + mb0 + nrow;
                    int row1 = brow0 + mb0 + 16 + nrow;
                    __builtin_nontemporal_store(
                        o0, reinterpret_cast<f32x4*>(&out[(size_t)row0 * GOUT + gs]));
                    __builtin_nontemporal_store(
                        o1, reinterpret_cast<f32x4*>(&out[(size_t)row1 * GOUT + gs]));
                }
            }
        }
    }
    }
}

extern "C" void kernel_launch(void* const* d_in, const int* in_sizes, int n_in,
                              void* d_out, int out_size, void* d_ws, size_t ws_size,
                              hipStream_t stream) {
    const float* gene  = (const float*)d_in[0];
    const float* W1    = (const float*)d_in[1];
    const float* b1    = (const float*)d_in[2];
    const float* W2    = (const float*)d_in[3];
    const float* b2    = (const float*)d_in[4];
    const float* pw    = (const float*)d_in[5];
    const float* Wout  = (const float*)d_in[6];
    const float* bout  = (const float*)d_in[7];
    const int* locs_gene   = (const int*)d_in[8];
    const int* locs_combos = (const int*)d_in[9];
    float* out = (float*)d_out;

    char* ws = (char*)d_ws;
    unsigned short* w1t    = (unsigned short*)(ws);
    unsigned short* w2t    = (unsigned short*)(ws + 32768);
    unsigned short* woutT  = (unsigned short*)(ws + 65536);
    unsigned short* poolbf = (unsigned short*)(ws + 65536 + (size_t)GPAD * 256);

    hipLaunchKernelGGL(prep_weights, dim3(32), dim3(256), 0, stream, W1, W2, w1t, w2t);
    hipLaunchKernelGGL(prep_wout, dim3((GPAD + 255) / 256), dim3(256), 0, stream, Wout, woutT);
    hipLaunchKernelGGL(encoder_kernel, dim3(NB / CPB), dim3(512), 0, stream,
                       gene, b1, b2, pw, locs_gene, locs_combos, w1t, w2t, poolbf);
    hipLaunchKernelGGL(out_gemm_a, dim3(GPAD / 128, 8), dim3(256), 0, stream,
                       poolbf, woutT, bout, out);
    hipLaunchKernelGGL(out_gemm_b, dim3(GPAD / 128, 8), dim3(256), 0, stream,
                       poolbf, woutT, bout, out);
}

// Round 15
// 208.237 us; speedup vs baseline: 2.9876x; 2.9876x over previous
//
#include <hip/hip_runtime.h>
#include <hip/hip_bf16.h>

#define GENES 20000
#define DD    128
#define PP    32
#define HH    128
#define NB    4096
#define GOUT  20000
#define GPAD  20096   // GOUT padded to multiple of 128
#define CPB   16      // combos per encoder block

typedef __attribute__((ext_vector_type(8))) short bf16x8;
typedef __attribute__((ext_vector_type(4))) float f32x4;

__device__ __forceinline__ unsigned short f2bf(float f) {
    unsigned int u = __float_as_uint(f);
    unsigned int lsb = (u >> 16) & 1u;
    u += 0x7fffu + lsb;                      // RTNE
    return (unsigned short)(u >> 16);
}
__device__ __forceinline__ float bf2f(unsigned short s) {
    return __uint_as_float(((unsigned int)s) << 16);
}

// XOR-swizzled ushort offset inside a [rows][128] bf16 tile (16B-chunk swizzle).
__device__ __forceinline__ int swz(int r, int c) {
    return r * 128 + (((c >> 3) ^ (r & 15)) << 3) + (c & 7);
}

// ---------------- K0a: W1,W2 -> swizzled bf16 transposed tiles ----------------
__global__ void prep_weights(const float* __restrict__ W1, const float* __restrict__ W2,
                             unsigned short* __restrict__ w1t, unsigned short* __restrict__ w2t) {
    int idx = blockIdx.x * 512 + threadIdx.x;
#pragma unroll
    for (int k = 0; k < 2; ++k, idx += 256) {
        int d = idx >> 7, h = idx & 127;
        int off = swz(h, d);       // W1T[h][d] = W1[d][h]
        w1t[off] = f2bf(W1[idx]);
        w2t[off] = f2bf(W2[idx]);
    }
}

// ---------------- K0b: Wout [128][20000] f32 -> WoutT [20096][128] bf16 -------
__global__ void prep_wout(const float* __restrict__ Wout, unsigned short* __restrict__ woutT) {
    int g = blockIdx.x * 256 + threadIdx.x;
    if (g >= GPAD) return;
    if (g < GOUT) {
        for (int d0 = 0; d0 < 128; d0 += 8) {
            unsigned short buf[8];
#pragma unroll
            for (int j = 0; j < 8; ++j) buf[j] = f2bf(Wout[(size_t)(d0 + j) * GOUT + g]);
            *reinterpret_cast<uint4*>(&woutT[(size_t)g * 128 + d0]) =
                *reinterpret_cast<const uint4*>(buf);
        }
    } else {
        uint4 z = {0u, 0u, 0u, 0u};
        for (int d0 = 0; d0 < 128; d0 += 8)
            *reinterpret_cast<uint4*>(&woutT[(size_t)g * 128 + d0]) = z;
    }
}

// ---------------- K1: persistent encoder, pipelined gather (R2 exact) ---------
__global__ __launch_bounds__(512) void encoder_kernel(
    const float* __restrict__ gene, const float* __restrict__ b1g,
    const float* __restrict__ b2g, const float* __restrict__ pwg,
    const int* __restrict__ locs_gene, const int* __restrict__ locs_combos,
    const unsigned short* __restrict__ w1t, const unsigned short* __restrict__ w2t,
    unsigned short* __restrict__ poolbf)
{
    __shared__ __align__(16) unsigned short w1L[128 * 128];     // 32 KB swizzled
    __shared__ __align__(16) unsigned short w2L[128 * 128];     // 32 KB swizzled
    __shared__ __align__(16) unsigned short aBuf[2][64 * 128];  // 2 x 16 KB swizzled
    __shared__ float wrow[64];
    __shared__ float pp[8][128];

    const int t = threadIdx.x;
    const int lane = t & 63, wv = t >> 6;
    const int nrow = lane & 15, kg = lane >> 4;
    const int mt = wv >> 1, nh = wv & 1;          // wave -> (M-tile, N-half)
    const int rA = mt * 16 + nrow;

    // ---- stage weights once per block
    {
        const uint4* s1 = reinterpret_cast<const uint4*>(w1t);
        const uint4* s2 = reinterpret_cast<const uint4*>(w2t);
        uint4* d1 = reinterpret_cast<uint4*>(w1L);
        uint4* d2 = reinterpret_cast<uint4*>(w2L);
        for (int i = t; i < 2048; i += 512) { d1[i] = s1[i]; d2[i] = s2[i]; }
    }
    // ---- per-thread invariants
    float b1r[4], b2r[4];
#pragma unroll
    for (int nt = 0; nt < 4; ++nt) {
        int c = nh * 64 + nt * 16 + nrow;
        b1r[nt] = b1g[c]; b2r[nt] = b2g[c];
    }
    const float pwl = pwg[lane & 31];

    // staging decomposition: thread -> (gene slot, d-quad, p-quad)
    const int sl = t >> 8;                 // 0..1 (which gene of the combo)
    const int w8 = t & 255;
    const int d0 = (w8 >> 3) * 4;          // 0,4,...,124
    const int pq = w8 & 7;                 // p-quad 0..7

    const int c0 = blockIdx.x * CPB;

    float4 pf[4];
    // ---- prologue: load + stage combo c0 into aBuf[0]
    {
        int g0 = locs_gene[2 * c0], g1 = locs_gene[2 * c0 + 1];
        const float* src = gene + (size_t)(sl ? g1 : g0) * 4096;
#pragma unroll
        for (int i = 0; i < 4; ++i)
            pf[i] = *reinterpret_cast<const float4*>(&src[(d0 + i) * 32 + pq * 4]);
#pragma unroll
        for (int q = 0; q < 4; ++q) {
            int r = sl * 32 + pq * 4 + q;
            unsigned int lo = (unsigned int)f2bf((&pf[0].x)[q]) |
                              ((unsigned int)f2bf((&pf[1].x)[q]) << 16);
            unsigned int hi = (unsigned int)f2bf((&pf[2].x)[q]) |
                              ((unsigned int)f2bf((&pf[3].x)[q]) << 16);
            uint2 v2 = {lo, hi};
            *reinterpret_cast<uint2*>(
                &aBuf[0][r * 128 + (((d0 >> 3) ^ (r & 15)) << 3) + (d0 & 7)]) = v2;
        }
    }
    __syncthreads();

    int cur = 0;
    for (int j = 0; j < CPB; ++j) {
        const int c = c0 + j;
        // ---- issue prefetch loads for combo c+1 (latency hides under MFMA)
        if (j + 1 < CPB) {
            int g0 = locs_gene[2 * (c + 1)], g1 = locs_gene[2 * (c + 1) + 1];
            const float* src = gene + (size_t)(sl ? g1 : g0) * 4096;
#pragma unroll
            for (int i = 0; i < 4; ++i)
                pf[i] = *reinterpret_cast<const float4*>(&src[(d0 + i) * 32 + pq * 4]);
        }
        const unsigned short* A = aBuf[cur];
        unsigned short* Aw = aBuf[cur];

        // ---- wave 0: per-row colsum -> mask -> softmax -> wrow[64]
        if (wv == 0) {
            float cs = 0.f;
#pragma unroll
            for (int cch = 0; cch < 16; ++cch) {
                int phys = cch ^ (lane & 15);
                bf16x8 v = *reinterpret_cast<const bf16x8*>(&A[lane * 128 + phys * 8]);
#pragma unroll
                for (int q = 0; q < 8; ++q) cs += bf2f((unsigned short)v[q]);
            }
            float other = __shfl_down(cs, 32);
            bool m = (cs != 0.f) || (other != 0.f);
            float logit = m ? pwl : -1e9f;
            float mx = logit;
#pragma unroll
            for (int o = 16; o >= 1; o >>= 1) mx = fmaxf(mx, __shfl_xor(mx, o, 32));
            float e = __expf(logit - mx);
            float se = e;
#pragma unroll
            for (int o = 16; o >= 1; o >>= 1) se += __shfl_xor(se, o, 32);
            float w = e / se;
            if (lane < 32) { wrow[lane] = w; wrow[lane + 32] = w; }
        }

        // ---- layer 1: H1 = leaky(A @ W1 + b1)
        bf16x8 afr[4];
#pragma unroll
        for (int ks = 0; ks < 4; ++ks) {
            int phys = (ks * 4 + kg) ^ (rA & 15);
            afr[ks] = *reinterpret_cast<const bf16x8*>(&A[rA * 128 + phys * 8]);
        }
        f32x4 acc1[4];
#pragma unroll
        for (int nt = 0; nt < 4; ++nt) {
            f32x4 acc = {0.f, 0.f, 0.f, 0.f};
            int n = nh * 64 + nt * 16 + nrow;
#pragma unroll
            for (int ks = 0; ks < 4; ++ks) {
                int phys = (ks * 4 + kg) ^ (n & 15);
                bf16x8 bfr = *reinterpret_cast<const bf16x8*>(&w1L[n * 128 + phys * 8]);
                acc = __builtin_amdgcn_mfma_f32_16x16x32_bf16(afr[ks], bfr, acc, 0, 0, 0);
            }
            acc1[nt] = acc;
        }
        __syncthreads();   // (1) all aBuf[cur] reads + wrow write done

        // ---- write H1 back into aBuf[cur] (swizzled)
#pragma unroll
        for (int nt = 0; nt < 4; ++nt) {
            int cc = nh * 64 + nt * 16 + nrow;
#pragma unroll
            for (int i = 0; i < 4; ++i) {
                int r = mt * 16 + kg * 4 + i;
                float x = acc1[nt][i] + b1r[nt];
                x = (x >= 0.f) ? x : 0.01f * x;
                Aw[swz(r, cc)] = f2bf(x);
            }
        }
        __syncthreads();   // (2) H1 visible

        // ---- layer 2 + leaky + weighted pooling
        bf16x8 afr2[4];
#pragma unroll
        for (int ks = 0; ks < 4; ++ks) {
            int phys = (ks * 4 + kg) ^ (rA & 15);
            afr2[ks] = *reinterpret_cast<const bf16x8*>(&A[rA * 128 + phys * 8]);
        }
        float wr[4];
#pragma unroll
        for (int i = 0; i < 4; ++i) wr[i] = wrow[mt * 16 + kg * 4 + i];
        float part[4];
#pragma unroll
        for (int nt = 0; nt < 4; ++nt) {
            f32x4 acc = {0.f, 0.f, 0.f, 0.f};
            int n = nh * 64 + nt * 16 + nrow;
#pragma unroll
            for (int ks = 0; ks < 4; ++ks) {
                int phys = (ks * 4 + kg) ^ (n & 15);
                bf16x8 bfr = *reinterpret_cast<const bf16x8*>(&w2L[n * 128 + phys * 8]);
                acc = __builtin_amdgcn_mfma_f32_16x16x32_bf16(afr2[ks], bfr, acc, 0, 0, 0);
            }
            float s = 0.f;
#pragma unroll
            for (int i = 0; i < 4; ++i) {
                float x = acc[i] + b2r[nt];
                x = (x >= 0.f) ? x : 0.01f * x;
                s += x * wr[i];
            }
            part[nt] = s;
        }
#pragma unroll
        for (int nt = 0; nt < 4; ++nt) {
            float v = part[nt];
            v += __shfl_xor(v, 16);
            v += __shfl_xor(v, 32);
            part[nt] = v;
        }
        if (lane < 16) {
#pragma unroll
            for (int nt = 0; nt < 4; ++nt) pp[wv][nh * 64 + nt * 16 + lane] = part[nt];
        }
        __syncthreads();   // (3) pp complete

        if (t < 128) {
            int base = t >> 6;
            float s = pp[base][t] + pp[base + 2][t] + pp[base + 4][t] + pp[base + 6][t];
            int seg = locs_combos[2 * c];
            poolbf[(size_t)seg * 128 + t] = f2bf(s);
        }
        // ---- stage combo c+1 into aBuf[cur^1]
        if (j + 1 < CPB) {
            unsigned short* B = aBuf[cur ^ 1];
#pragma unroll
            for (int q = 0; q < 4; ++q) {
                int r = sl * 32 + pq * 4 + q;
                unsigned int lo = (unsigned int)f2bf((&pf[0].x)[q]) |
                                  ((unsigned int)f2bf((&pf[1].x)[q]) << 16);
                unsigned int hi = (unsigned int)f2bf((&pf[2].x)[q]) |
                                  ((unsigned int)f2bf((&pf[3].x)[q]) << 16);
                uint2 v2 = {lo, hi};
                *reinterpret_cast<uint2*>(
                    &B[r * 128 + (((d0 >> 3) ^ (r & 15)) << 3) + (d0 & 7)]) = v2;
            }
            cur ^= 1;
        }
        __syncthreads();   // (4) aBuf[next] ready; pp reads done
    }
}

// ---------------- K2: out_gemm, full-width LDS tile + 512B nt store spans -----
// R14 counters: FETCH 11 MB (reads solved), write BW 4.3 TB/s (53%) with
// 64-256B segments, WRITE amplified 1.37x. Fix: deposit BOTH p-halves into a
// [128][132] f32 tile, then store each row as a 512B contiguous span (32
// lanes x 16B), 8 rows per block instruction — full 128B-line coverage.
__global__ __launch_bounds__(256, 2) void out_gemm(
    const unsigned short* __restrict__ poolbf, const unsigned short* __restrict__ woutT,
    const float* __restrict__ boutg, float* __restrict__ out)
{
    __shared__ float tile[128][132];           // 67.6 KB -> 2 blocks/CU
    const int t = threadIdx.x;
    const int lane = t & 63, wv = t >> 6;
    const int nrow = lane & 15, kg = lane >> 4;
    const int nb0 = blockIdx.x * 128;          // g base
    const int mb0 = wv * 32;                   // b offset inside subtile

#pragma unroll 1
    for (int sub = 0; sub < 4; ++sub) {
        const int brow0 = (blockIdx.y * 4 + sub) * 128;
        // ---- B-frags once per subtile
        bf16x8 bfr[2][4];
#pragma unroll
        for (int bt = 0; bt < 2; ++bt) {
            int row = brow0 + mb0 + bt * 16 + nrow;
#pragma unroll
            for (int ks = 0; ks < 4; ++ks)
                bfr[bt][ks] = *reinterpret_cast<const bf16x8*>(
                    &poolbf[(size_t)row * 128 + ks * 32 + kg * 8]);
        }
#pragma unroll 1
        for (int p = 0; p < 2; ++p) {
            // A-frags for this g-half (L2-hot after sub 0)
            bf16x8 afr[4][4];
#pragma unroll
            for (int q = 0; q < 4; ++q) {
                int g = nb0 + (p * 4 + q) * 16 + nrow;
#pragma unroll
                for (int ks = 0; ks < 4; ++ks)
                    afr[q][ks] = *reinterpret_cast<const bf16x8*>(
                        &woutT[(size_t)g * 128 + ks * 32 + kg * 8]);
            }
            // MFMA 64 g x 128 b, deposit bias-added f32 into tile
#pragma unroll
            for (int q = 0; q < 4; ++q) {
                f32x4 a0 = {0.f, 0.f, 0.f, 0.f}, a1 = {0.f, 0.f, 0.f, 0.f};
#pragma unroll
                for (int ks = 0; ks < 4; ++ks) {
                    a0 = __builtin_amdgcn_mfma_f32_16x16x32_bf16(afr[q][ks], bfr[0][ks], a0, 0, 0, 0);
                    a1 = __builtin_amdgcn_mfma_f32_16x16x32_bf16(afr[q][ks], bfr[1][ks], a1, 0, 0, 0);
                }
                int gcol = nb0 + (p * 4 + q) * 16 + kg * 4;
                float4 b4 = {0.f, 0.f, 0.f, 0.f};
                if (gcol < GOUT) b4 = *reinterpret_cast<const float4*>(&boutg[gcol]);
                int gl = p * 64 + q * 16 + kg * 4;
                float4 o0, o1;
                o0.x = a0[0] + b4.x; o0.y = a0[1] + b4.y; o0.z = a0[2] + b4.z; o0.w = a0[3] + b4.w;
                o1.x = a1[0] + b4.x; o1.y = a1[1] + b4.y; o1.z = a1[2] + b4.z; o1.w = a1[3] + b4.w;
                *reinterpret_cast<float4*>(&tile[mb0 + nrow][gl]) = o0;
                *reinterpret_cast<float4*>(&tile[mb0 + 16 + nrow][gl]) = o1;
            }
        }
        __syncthreads();   // full 128x128 tile ready
        // ---- stores: each row = 512B contiguous (32 lanes x 16B), 8 rows/instr
        {
            int cl = (t & 31) * 4;                     // col 0..124
            int gcol = nb0 + cl;
            if (gcol < GOUT) {
#pragma unroll
                for (int rnd = 0; rnd < 16; ++rnd) {
                    int rl = rnd * 8 + (t >> 5);       // row 0..127
                    f32x4 v = *reinterpret_cast<const f32x4*>(&tile[rl][cl]);
                    __builtin_nontemporal_store(
                        v, reinterpret_cast<f32x4*>(&out[(size_t)(brow0 + rl) * GOUT + gcol]));
                }
            }
        }
        __syncthreads();   // store phase done before next subtile's deposits
    }
}

extern "C" void kernel_launch(void* const* d_in, const int* in_sizes, int n_in,
                              void* d_out, int out_size, void* d_ws, size_t ws_size,
                              hipStream_t stream) {
    const float* gene  = (const float*)d_in[0];
    const float* W1    = (const float*)d_in[1];
    const float* b1    = (const float*)d_in[2];
    const float* W2    = (const float*)d_in[3];
    const float* b2    = (const float*)d_in[4];
    const float* pw    = (const float*)d_in[5];
    const float* Wout  = (const float*)d_in[6];
    const float* bout  = (const float*)d_in[7];
    const int* locs_gene   = (const int*)d_in[8];
    const int* locs_combos = (const int*)d_in[9];
    float* out = (float*)d_out;

    char* ws = (char*)d_ws;
    unsigned short* w1t    = (unsigned short*)(ws);
    unsigned short* w2t    = (unsigned short*)(ws + 32768);
    unsigned short* woutT  = (unsigned short*)(ws + 65536);
    unsigned short* poolbf = (unsigned short*)(ws + 65536 + (size_t)GPAD * 256);

    hipLaunchKernelGGL(prep_weights, dim3(32), dim3(256), 0, stream, W1, W2, w1t, w2t);
    hipLaunchKernelGGL(prep_wout, dim3((GPAD + 255) / 256), dim3(256), 0, stream, Wout, woutT);
    hipLaunchKernelGGL(encoder_kernel, dim3(NB / CPB), dim3(512), 0, stream,
                       gene, b1, b2, pw, locs_gene, locs_combos, w1t, w2t, poolbf);
    hipLaunchKernelGGL(out_gemm, dim3(GPAD / 128, 8), dim3(256), 0, stream,
                       poolbf, woutT, bout, out);
}

// Round 16
// 174.446 us; speedup vs baseline: 3.5663x; 1.1937x over previous
//
#include <hip/hip_runtime.h>
#include <hip/hip_bf16.h>

#define GENES 20000
#define DD    128
#define PP    32
#define HH    128
#define NB    4096
#define GOUT  20000
#define GPAD  20096   // GOUT padded to multiple of 128
#define CPB   16      // combos per encoder block

typedef __attribute__((ext_vector_type(8))) short bf16x8;
typedef __attribute__((ext_vector_type(4))) float f32x4;

__device__ __forceinline__ unsigned short f2bf(float f) {
    unsigned int u = __float_as_uint(f);
    unsigned int lsb = (u >> 16) & 1u;
    u += 0x7fffu + lsb;                      // RTNE
    return (unsigned short)(u >> 16);
}
__device__ __forceinline__ float bf2f(unsigned short s) {
    return __uint_as_float(((unsigned int)s) << 16);
}

// XOR-swizzled ushort offset inside a [rows][128] bf16 tile (16B-chunk swizzle).
__device__ __forceinline__ int swz(int r, int c) {
    return r * 128 + (((c >> 3) ^ (r & 15)) << 3) + (c & 7);
}

// ---------------- K0a: W1,W2 -> swizzled bf16 transposed tiles ----------------
__global__ void prep_weights(const float* __restrict__ W1, const float* __restrict__ W2,
                             unsigned short* __restrict__ w1t, unsigned short* __restrict__ w2t) {
    int idx = blockIdx.x * 512 + threadIdx.x;
#pragma unroll
    for (int k = 0; k < 2; ++k, idx += 256) {
        int d = idx >> 7, h = idx & 127;
        int off = swz(h, d);       // W1T[h][d] = W1[d][h]
        w1t[off] = f2bf(W1[idx]);
        w2t[off] = f2bf(W2[idx]);
    }
}

// ---------------- K0b: Wout [128][20000] f32 -> WoutT [20096][128] bf16 -------
__global__ void prep_wout(const float* __restrict__ Wout, unsigned short* __restrict__ woutT) {
    int g = blockIdx.x * 256 + threadIdx.x;
    if (g >= GPAD) return;
    if (g < GOUT) {
        for (int d0 = 0; d0 < 128; d0 += 8) {
            unsigned short buf[8];
#pragma unroll
            for (int j = 0; j < 8; ++j) buf[j] = f2bf(Wout[(size_t)(d0 + j) * GOUT + g]);
            *reinterpret_cast<uint4*>(&woutT[(size_t)g * 128 + d0]) =
                *reinterpret_cast<const uint4*>(buf);
        }
    } else {
        uint4 z = {0u, 0u, 0u, 0u};
        for (int d0 = 0; d0 < 128; d0 += 8)
            *reinterpret_cast<uint4*>(&woutT[(size_t)g * 128 + d0]) = z;
    }
}

// ---------------- K1: persistent encoder, pipelined gather (R2 exact) ---------
__global__ __launch_bounds__(512) void encoder_kernel(
    const float* __restrict__ gene, const float* __restrict__ b1g,
    const float* __restrict__ b2g, const float* __restrict__ pwg,
    const int* __restrict__ locs_gene, const int* __restrict__ locs_combos,
    const unsigned short* __restrict__ w1t, const unsigned short* __restrict__ w2t,
    unsigned short* __restrict__ poolbf)
{
    __shared__ __align__(16) unsigned short w1L[128 * 128];     // 32 KB swizzled
    __shared__ __align__(16) unsigned short w2L[128 * 128];     // 32 KB swizzled
    __shared__ __align__(16) unsigned short aBuf[2][64 * 128];  // 2 x 16 KB swizzled
    __shared__ float wrow[64];
    __shared__ float pp[8][128];

    const int t = threadIdx.x;
    const int lane = t & 63, wv = t >> 6;
    const int nrow = lane & 15, kg = lane >> 4;
    const int mt = wv >> 1, nh = wv & 1;          // wave -> (M-tile, N-half)
    const int rA = mt * 16 + nrow;

    // ---- stage weights once per block
    {
        const uint4* s1 = reinterpret_cast<const uint4*>(w1t);
        const uint4* s2 = reinterpret_cast<const uint4*>(w2t);
        uint4* d1 = reinterpret_cast<uint4*>(w1L);
        uint4* d2 = reinterpret_cast<uint4*>(w2L);
        for (int i = t; i < 2048; i += 512) { d1[i] = s1[i]; d2[i] = s2[i]; }
    }
    // ---- per-thread invariants
    float b1r[4], b2r[4];
#pragma unroll
    for (int nt = 0; nt < 4; ++nt) {
        int c = nh * 64 + nt * 16 + nrow;
        b1r[nt] = b1g[c]; b2r[nt] = b2g[c];
    }
    const float pwl = pwg[lane & 31];

    // staging decomposition: thread -> (gene slot, d-quad, p-quad)
    const int sl = t >> 8;                 // 0..1 (which gene of the combo)
    const int w8 = t & 255;
    const int d0 = (w8 >> 3) * 4;          // 0,4,...,124
    const int pq = w8 & 7;                 // p-quad 0..7

    const int c0 = blockIdx.x * CPB;

    float4 pf[4];
    // ---- prologue: load + stage combo c0 into aBuf[0]
    {
        int g0 = locs_gene[2 * c0], g1 = locs_gene[2 * c0 + 1];
        const float* src = gene + (size_t)(sl ? g1 : g0) * 4096;
#pragma unroll
        for (int i = 0; i < 4; ++i)
            pf[i] = *reinterpret_cast<const float4*>(&src[(d0 + i) * 32 + pq * 4]);
#pragma unroll
        for (int q = 0; q < 4; ++q) {
            int r = sl * 32 + pq * 4 + q;
            unsigned int lo = (unsigned int)f2bf((&pf[0].x)[q]) |
                              ((unsigned int)f2bf((&pf[1].x)[q]) << 16);
            unsigned int hi = (unsigned int)f2bf((&pf[2].x)[q]) |
                              ((unsigned int)f2bf((&pf[3].x)[q]) << 16);
            uint2 v2 = {lo, hi};
            *reinterpret_cast<uint2*>(
                &aBuf[0][r * 128 + (((d0 >> 3) ^ (r & 15)) << 3) + (d0 & 7)]) = v2;
        }
    }
    __syncthreads();

    int cur = 0;
    for (int j = 0; j < CPB; ++j) {
        const int c = c0 + j;
        // ---- issue prefetch loads for combo c+1 (latency hides under MFMA)
        if (j + 1 < CPB) {
            int g0 = locs_gene[2 * (c + 1)], g1 = locs_gene[2 * (c + 1) + 1];
            const float* src = gene + (size_t)(sl ? g1 : g0) * 4096;
#pragma unroll
            for (int i = 0; i < 4; ++i)
                pf[i] = *reinterpret_cast<const float4*>(&src[(d0 + i) * 32 + pq * 4]);
        }
        const unsigned short* A = aBuf[cur];
        unsigned short* Aw = aBuf[cur];

        // ---- wave 0: per-row colsum -> mask -> softmax -> wrow[64]
        if (wv == 0) {
            float cs = 0.f;
#pragma unroll
            for (int cch = 0; cch < 16; ++cch) {
                int phys = cch ^ (lane & 15);
                bf16x8 v = *reinterpret_cast<const bf16x8*>(&A[lane * 128 + phys * 8]);
#pragma unroll
                for (int q = 0; q < 8; ++q) cs += bf2f((unsigned short)v[q]);
            }
            float other = __shfl_down(cs, 32);
            bool m = (cs != 0.f) || (other != 0.f);
            float logit = m ? pwl : -1e9f;
            float mx = logit;
#pragma unroll
            for (int o = 16; o >= 1; o >>= 1) mx = fmaxf(mx, __shfl_xor(mx, o, 32));
            float e = __expf(logit - mx);
            float se = e;
#pragma unroll
            for (int o = 16; o >= 1; o >>= 1) se += __shfl_xor(se, o, 32);
            float w = e / se;
            if (lane < 32) { wrow[lane] = w; wrow[lane + 32] = w; }
        }

        // ---- layer 1: H1 = leaky(A @ W1 + b1)
        bf16x8 afr[4];
#pragma unroll
        for (int ks = 0; ks < 4; ++ks) {
            int phys = (ks * 4 + kg) ^ (rA & 15);
            afr[ks] = *reinterpret_cast<const bf16x8*>(&A[rA * 128 + phys * 8]);
        }
        f32x4 acc1[4];
#pragma unroll
        for (int nt = 0; nt < 4; ++nt) {
            f32x4 acc = {0.f, 0.f, 0.f, 0.f};
            int n = nh * 64 + nt * 16 + nrow;
#pragma unroll
            for (int ks = 0; ks < 4; ++ks) {
                int phys = (ks * 4 + kg) ^ (n & 15);
                bf16x8 bfr = *reinterpret_cast<const bf16x8*>(&w1L[n * 128 + phys * 8]);
                acc = __builtin_amdgcn_mfma_f32_16x16x32_bf16(afr[ks], bfr, acc, 0, 0, 0);
            }
            acc1[nt] = acc;
        }
        __syncthreads();   // (1) all aBuf[cur] reads + wrow write done

        // ---- write H1 back into aBuf[cur] (swizzled)
#pragma unroll
        for (int nt = 0; nt < 4; ++nt) {
            int cc = nh * 64 + nt * 16 + nrow;
#pragma unroll
            for (int i = 0; i < 4; ++i) {
                int r = mt * 16 + kg * 4 + i;
                float x = acc1[nt][i] + b1r[nt];
                x = (x >= 0.f) ? x : 0.01f * x;
                Aw[swz(r, cc)] = f2bf(x);
            }
        }
        __syncthreads();   // (2) H1 visible

        // ---- layer 2 + leaky + weighted pooling
        bf16x8 afr2[4];
#pragma unroll
        for (int ks = 0; ks < 4; ++ks) {
            int phys = (ks * 4 + kg) ^ (rA & 15);
            afr2[ks] = *reinterpret_cast<const bf16x8*>(&A[rA * 128 + phys * 8]);
        }
        float wr[4];
#pragma unroll
        for (int i = 0; i < 4; ++i) wr[i] = wrow[mt * 16 + kg * 4 + i];
        float part[4];
#pragma unroll
        for (int nt = 0; nt < 4; ++nt) {
            f32x4 acc = {0.f, 0.f, 0.f, 0.f};
            int n = nh * 64 + nt * 16 + nrow;
#pragma unroll
            for (int ks = 0; ks < 4; ++ks) {
                int phys = (ks * 4 + kg) ^ (n & 15);
                bf16x8 bfr = *reinterpret_cast<const bf16x8*>(&w2L[n * 128 + phys * 8]);
                acc = __builtin_amdgcn_mfma_f32_16x16x32_bf16(afr2[ks], bfr, acc, 0, 0, 0);
            }
            float s = 0.f;
#pragma unroll
            for (int i = 0; i < 4; ++i) {
                float x = acc[i] + b2r[nt];
                x = (x >= 0.f) ? x : 0.01f * x;
                s += x * wr[i];
            }
            part[nt] = s;
        }
#pragma unroll
        for (int nt = 0; nt < 4; ++nt) {
            float v = part[nt];
            v += __shfl_xor(v, 16);
            v += __shfl_xor(v, 32);
            part[nt] = v;
        }
        if (lane < 16) {
#pragma unroll
            for (int nt = 0; nt < 4; ++nt) pp[wv][nh * 64 + nt * 16 + lane] = part[nt];
        }
        __syncthreads();   // (3) pp complete

        if (t < 128) {
            int base = t >> 6;
            float s = pp[base][t] + pp[base + 2][t] + pp[base + 4][t] + pp[base + 6][t];
            int seg = locs_combos[2 * c];
            poolbf[(size_t)seg * 128 + t] = f2bf(s);
        }
        // ---- stage combo c+1 into aBuf[cur^1]
        if (j + 1 < CPB) {
            unsigned short* B = aBuf[cur ^ 1];
#pragma unroll
            for (int q = 0; q < 4; ++q) {
                int r = sl * 32 + pq * 4 + q;
                unsigned int lo = (unsigned int)f2bf((&pf[0].x)[q]) |
                                  ((unsigned int)f2bf((&pf[1].x)[q]) << 16);
                unsigned int hi = (unsigned int)f2bf((&pf[2].x)[q]) |
                                  ((unsigned int)f2bf((&pf[3].x)[q]) << 16);
                uint2 v2 = {lo, hi};
                *reinterpret_cast<uint2*>(
                    &B[r * 128 + (((d0 >> 3) ^ (r & 15)) << 3) + (d0 & 7)]) = v2;
            }
            cur ^= 1;
        }
        __syncthreads();   // (4) aBuf[next] ready; pp reads done
    }
}

// ---------------- K2: out_gemm, B-amortized + NONTEMPORAL C stores (R13) ------
// Measured optimum of the store trade curve: 256B spans @ 3 blocks/CU (R13)
// beats 64B direct (R14 K2b, 4.3 TB/s) and 512B spans @ 2 blocks/CU (R15).
// FETCH is 11 MB/pass (nt protects operand residency, R14).
__global__ __launch_bounds__(256, 3) void out_gemm(
    const unsigned short* __restrict__ poolbf, const unsigned short* __restrict__ woutT,
    const float* __restrict__ boutg, float* __restrict__ out)
{
    __shared__ float tile[128][68];            // 34.8 KB
    const int t = threadIdx.x;
    const int lane = t & 63, wv = t >> 6;
    const int nrow = lane & 15, kg = lane >> 4;
    const int nb0 = blockIdx.x * 128;          // g base (fastest-varying blocks)
    const int mb0 = wv * 32;                   // b offset inside subtile

#pragma unroll 1
    for (int p = 0; p < 2; ++p) {
        // ---- A-frags for this g-half, held across all 4 b-subtiles (64 VGPR)
        bf16x8 afr[4][4];
#pragma unroll
        for (int q = 0; q < 4; ++q) {
            int g = nb0 + (p * 4 + q) * 16 + nrow;
#pragma unroll
            for (int ks = 0; ks < 4; ++ks)
                afr[q][ks] = *reinterpret_cast<const bf16x8*>(
                    &woutT[(size_t)g * 128 + ks * 32 + kg * 8]);
        }
#pragma unroll 1
        for (int sub = 0; sub < 4; ++sub) {
            const int brow0 = (blockIdx.y * 4 + sub) * 128;
            // ---- B-frags: pooled rows (L2-resident; nt stores stop thrash)
            bf16x8 bfr[2][4];
#pragma unroll
            for (int bt = 0; bt < 2; ++bt) {
                int row = brow0 + mb0 + bt * 16 + nrow;
#pragma unroll
                for (int ks = 0; ks < 4; ++ks)
                    bfr[bt][ks] = *reinterpret_cast<const bf16x8*>(
                        &poolbf[(size_t)row * 128 + ks * 32 + kg * 8]);
            }
            // ---- MFMA 64 g x 128 b
            f32x4 acc[4][2];
#pragma unroll
            for (int q = 0; q < 4; ++q) {
                f32x4 a0 = {0.f, 0.f, 0.f, 0.f}, a1 = {0.f, 0.f, 0.f, 0.f};
#pragma unroll
                for (int ks = 0; ks < 4; ++ks) {
                    a0 = __builtin_amdgcn_mfma_f32_16x16x32_bf16(afr[q][ks], bfr[0][ks], a0, 0, 0, 0);
                    a1 = __builtin_amdgcn_mfma_f32_16x16x32_bf16(afr[q][ks], bfr[1][ks], a1, 0, 0, 0);
                }
                acc[q][0] = a0; acc[q][1] = a1;
            }
            __syncthreads();   // prior store-phase LDS reads complete
            // ---- deposit bias-added f32 into LDS
#pragma unroll
            for (int q = 0; q < 4; ++q) {
                int gcol = nb0 + (p * 4 + q) * 16 + kg * 4;
                float4 b4 = {0.f, 0.f, 0.f, 0.f};
                if (gcol < GOUT) b4 = *reinterpret_cast<const float4*>(&boutg[gcol]);
                int gl = q * 16 + kg * 4;
#pragma unroll
                for (int bt = 0; bt < 2; ++bt) {
                    int row = mb0 + bt * 16 + nrow;
                    float4 o;
                    o.x = acc[q][bt][0] + b4.x; o.y = acc[q][bt][1] + b4.y;
                    o.z = acc[q][bt][2] + b4.z; o.w = acc[q][bt][3] + b4.w;
                    *reinterpret_cast<float4*>(&tile[row][gl]) = o;
                }
            }
            __syncthreads();   // tile ready
            // ---- coalesced NONTEMPORAL stores: 256 B contiguous per 16 lanes
            int cl = (t & 15) * 4;
            int gcol = nb0 + p * 64 + cl;
            if (gcol < GOUT) {
#pragma unroll
                for (int rnd = 0; rnd < 8; ++rnd) {
                    int rl = rnd * 16 + (t >> 4);
                    f32x4 v = *reinterpret_cast<const f32x4*>(&tile[rl][cl]);
                    __builtin_nontemporal_store(
                        v, reinterpret_cast<f32x4*>(&out[(size_t)(brow0 + rl) * GOUT + gcol]));
                }
            }
        }
    }
}

extern "C" void kernel_launch(void* const* d_in, const int* in_sizes, int n_in,
                              void* d_out, int out_size, void* d_ws, size_t ws_size,
                              hipStream_t stream) {
    const float* gene  = (const float*)d_in[0];
    const float* W1    = (const float*)d_in[1];
    const float* b1    = (const float*)d_in[2];
    const float* W2    = (const float*)d_in[3];
    const float* b2    = (const float*)d_in[4];
    const float* pw    = (const float*)d_in[5];
    const float* Wout  = (const float*)d_in[6];
    const float* bout  = (const float*)d_in[7];
    const int* locs_gene   = (const int*)d_in[8];
    const int* locs_combos = (const int*)d_in[9];
    float* out = (float*)d_out;

    char* ws = (char*)d_ws;
    unsigned short* w1t    = (unsigned short*)(ws);
    unsigned short* w2t    = (unsigned short*)(ws + 32768);
    unsigned short* woutT  = (unsigned short*)(ws + 65536);
    unsigned short* poolbf = (unsigned short*)(ws + 65536 + (size_t)GPAD * 256);

    hipLaunchKernelGGL(prep_weights, dim3(32), dim3(256), 0, stream, W1, W2, w1t, w2t);
    hipLaunchKernelGGL(prep_wout, dim3((GPAD + 255) / 256), dim3(256), 0, stream, Wout, woutT);
    hipLaunchKernelGGL(encoder_kernel, dim3(NB / CPB), dim3(512), 0, stream,
                       gene, b1, b2, pw, locs_gene, locs_combos, w1t, w2t, poolbf);
    hipLaunchKernelGGL(out_gemm, dim3(GPAD / 128, 8), dim3(256), 0, stream,
                       poolbf, woutT, bout, out);
}